// Round 1
// baseline (149.227 us; speedup 1.0000x reference)
//
#include <hip/hip_runtime.h>
#include <hip/hip_bf16.h>

typedef __attribute__((ext_vector_type(8))) __bf16 bf16x8;
typedef __attribute__((ext_vector_type(4))) float f32x4;

__device__ __forceinline__ f32x4 mfma16(bf16x8 a, bf16x8 b, f32x4 c) {
    return __builtin_amdgcn_mfma_f32_16x16x32_bf16(a, b, c, 0, 0, 0);
}

__device__ __forceinline__ unsigned short f2bf(float x) {
    union { float f; unsigned int u; } cv; cv.f = x;
    unsigned int r = cv.u + 0x7FFFu + ((cv.u >> 16) & 1u);
    return (unsigned short)(r >> 16);
}

__device__ __forceinline__ void gload_lds16(const void* g, void* l) {
    __builtin_amdgcn_global_load_lds(
        (const __attribute__((address_space(1))) unsigned int*)g,
        (__attribute__((address_space(3))) unsigned int*)l, 16, 0, 0);
}

// ---------------- Kernel 1: weight norm -> bf16 normalized weights ----------
// Wn[proj][o][c] = g[o] * v[o][c] / ||v[o]||, proj in {q,k,v}
__global__ __launch_bounds__(64) void wn_kernel(
    const float* __restrict__ Wq_v, const float* __restrict__ Wq_g,
    const float* __restrict__ Wk_v, const float* __restrict__ Wk_g,
    const float* __restrict__ Wv_v, const float* __restrict__ Wv_g,
    unsigned short* __restrict__ Wn)
{
    int idx = blockIdx.x;            // proj*512 + o
    int proj = idx >> 9, o = idx & 511;
    const float* v = (proj == 0 ? Wq_v : proj == 1 ? Wk_v : Wv_v) + (size_t)o * 384;
    const float* g = (proj == 0 ? Wq_g : proj == 1 ? Wk_g : Wv_g);
    int lane = threadIdx.x;
    float vals[6];
    float ss = 0.f;
#pragma unroll
    for (int i = 0; i < 6; ++i) { vals[i] = v[lane + i * 64]; ss += vals[i] * vals[i]; }
#pragma unroll
    for (int off = 1; off < 64; off <<= 1) ss += __shfl_xor(ss, off, 64);
    float scale = g[o] * rsqrtf(ss);
    unsigned short* dst = Wn + ((size_t)proj * 512 + o) * 384;
#pragma unroll
    for (int i = 0; i < 6; ++i) dst[lane + i * 64] = f2bf(vals[i] * scale);
}

// ---------------- Kernel 2: transpose+convert q,k: [B][Cin][S] f32 -> [B][S][Cin] bf16
__global__ __launch_bounds__(256) void transpose_kernel(
    const float* __restrict__ q, const float* __restrict__ k,
    unsigned short* __restrict__ qT, unsigned short* __restrict__ kT)
{
    __shared__ float tile[32][33];
    int z = blockIdx.z;
    const float* src = (z < 8 ? q : k) + (size_t)(z & 7) * 384 * 1024;
    unsigned short* dst = (z < 8 ? qT : kT) + (size_t)(z & 7) * 1024 * 384;
    int c0 = blockIdx.y * 32, s0 = blockIdx.x * 32;
    int tx = threadIdx.x, ty = threadIdx.y;
#pragma unroll
    for (int j = 0; j < 4; ++j)
        tile[ty + j * 8][tx] = src[(size_t)(c0 + ty + j * 8) * 1024 + s0 + tx];
    __syncthreads();
#pragma unroll
    for (int j = 0; j < 4; ++j)
        dst[(size_t)(s0 + ty + j * 8) * 384 + c0 + tx] = f2bf(tile[tx][ty + j * 8]);
}

// ---------------- Kernel 3: projection GEMM (bf16 MFMA) ---------------------
// Out[b][s][c] = sum_i A[b][s][i] * W[c][i] + bias[c]; M=1024,N=512,K=384
__global__ __launch_bounds__(256) void proj_gemm(
    const unsigned short* __restrict__ qT, const unsigned short* __restrict__ kT,
    const unsigned short* __restrict__ Wn,
    const float* __restrict__ bq, const float* __restrict__ bk, const float* __restrict__ bv,
    unsigned short* __restrict__ Qp, unsigned short* __restrict__ Kp,
    unsigned short* __restrict__ Vp)
{
    __shared__ unsigned short Asm[128 * 32];
    __shared__ unsigned short Bsm[128 * 32];
    int zb = blockIdx.z; int proj = zb >> 3, b = zb & 7;
    const unsigned short* A = (proj == 0 ? qT : kT) + (size_t)b * 1024 * 384;
    const unsigned short* Bw = Wn + (size_t)proj * 512 * 384;
    const float* bias = proj == 0 ? bq : (proj == 1 ? bk : bv);
    unsigned short* Out = (proj == 0 ? Qp : proj == 1 ? Kp : Vp) + (size_t)b * 1024 * 512;
    int m0 = blockIdx.x * 128, n0 = blockIdx.y * 128;
    int t = threadIdx.x, w = t >> 6, lane = t & 63;
    int fr = lane & 15, fq = lane >> 4;
    int wm = (w >> 1) * 64, wn = (w & 1) * 64;

    f32x4 acc[4][4];
#pragma unroll
    for (int i = 0; i < 4; ++i)
#pragma unroll
        for (int j = 0; j < 4; ++j) acc[i][j] = (f32x4){0.f, 0.f, 0.f, 0.f};

    const unsigned short* asrc = A + (size_t)(m0 + w * 16 + (lane >> 2)) * 384 + (lane & 3) * 8;
    const unsigned short* bsrc = Bw + (size_t)(n0 + w * 16 + (lane >> 2)) * 384 + (lane & 3) * 8;
    unsigned short* albase = Asm + w * 512;   // w*1024 bytes, wave-uniform
    unsigned short* blbase = Bsm + w * 512;

    for (int k0 = 0; k0 < 384; k0 += 32) {
        __syncthreads();
        gload_lds16(asrc + k0, albase);
        gload_lds16(asrc + k0 + (size_t)64 * 384, albase + 2048);
        gload_lds16(bsrc + k0, blbase);
        gload_lds16(bsrc + k0 + (size_t)64 * 384, blbase + 2048);
        asm volatile("s_waitcnt vmcnt(0)" ::: "memory");
        __syncthreads();
        bf16x8 af[4], bfr[4];
#pragma unroll
        for (int i = 0; i < 4; ++i)
            af[i] = *(const bf16x8*)&Asm[(wm + i * 16 + fr) * 32 + fq * 8];
#pragma unroll
        for (int i = 0; i < 4; ++i)
            bfr[i] = *(const bf16x8*)&Bsm[(wn + i * 16 + fr) * 32 + fq * 8];
#pragma unroll
        for (int mi = 0; mi < 4; ++mi)
#pragma unroll
            for (int ni = 0; ni < 4; ++ni)
                acc[mi][ni] = mfma16(af[mi], bfr[ni], acc[mi][ni]);
    }
#pragma unroll
    for (int mi = 0; mi < 4; ++mi)
#pragma unroll
        for (int ni = 0; ni < 4; ++ni)
#pragma unroll
            for (int r = 0; r < 4; ++r) {
                int c = n0 + wn + ni * 16 + fr;
                int s = m0 + wm + mi * 16 + fq * 4 + r;
                Out[(size_t)s * 512 + c] = f2bf(acc[mi][ni][r] + bias[c]);
            }
}

// ---------------- Kernel 4: flash attention, causal (k < q), row0 zeroed ----
__global__ __launch_bounds__(256) void attn_kernel(
    const unsigned short* __restrict__ Qp, const unsigned short* __restrict__ Kp,
    const unsigned short* __restrict__ Vp, float* __restrict__ out)
{
    __shared__ unsigned short VT[64][40];       // V tile transposed [d][k], padded
    __shared__ unsigned short Pl[4][16][40];    // per-wave P tile [q][k], padded
    int qt = blockIdx.x, bh = blockIdx.y;
    int b = bh >> 3, h = bh & 7;
    int t = threadIdx.x, w = t >> 6, lane = t & 63;
    int fr = lane & 15, fq = lane >> 4;
    const size_t base = ((size_t)b * 1024) * 512 + h * 64;
    const unsigned short* Qb = Qp + base;
    const unsigned short* Kb = Kp + base;
    const unsigned short* Vb = Vp + base;
    int row0 = qt * 64 + w * 16;

    bf16x8 qf0 = *(const bf16x8*)(Qb + (size_t)(row0 + fr) * 512 + fq * 8);
    bf16x8 qf1 = *(const bf16x8*)(Qb + (size_t)(row0 + fr) * 512 + 32 + fq * 8);

    f32x4 O[4];
#pragma unroll
    for (int f = 0; f < 4; ++f) O[f] = (f32x4){0.f, 0.f, 0.f, 0.f};
    float M[4], L[4];
#pragma unroll
    for (int r = 0; r < 4; ++r) { M[r] = -1e30f; L[r] = 0.f; }

    int nt = (qt * 64 + 62) / 32 + 1;   // tiles covering keys 0..qend-2
    for (int kt = 0; kt < nt; ++kt) {
        int kbase = kt * 32;
        __syncthreads();
        {   // stage V tile transposed: VT[d][k]
            const unsigned short* vsrc = Vb + (size_t)(kbase + (t >> 3)) * 512 + (t & 7) * 8;
            float4 raw = *(const float4*)vsrc;
            const unsigned short* pv = (const unsigned short*)&raw;
            int dbase = (t & 7) * 8, kk = t >> 3;
#pragma unroll
            for (int j = 0; j < 8; ++j) VT[dbase + j][kk] = pv[j];
        }
        __syncthreads();
        if (kbase >= row0 + 15) continue;   // wave-uniform: tile fully masked

        // QK^T: S[q][key], keys split in two 16-groups
        f32x4 Sa = (f32x4){0.f, 0.f, 0.f, 0.f};
        f32x4 Sb = (f32x4){0.f, 0.f, 0.f, 0.f};
        const unsigned short* kr0 = Kb + (size_t)(kbase + fr) * 512 + fq * 8;
        const unsigned short* kr1 = Kb + (size_t)(kbase + 16 + fr) * 512 + fq * 8;
        bf16x8 k0a = *(const bf16x8*)kr0;
        bf16x8 k0b = *(const bf16x8*)(kr0 + 32);
        bf16x8 k1a = *(const bf16x8*)kr1;
        bf16x8 k1b = *(const bf16x8*)(kr1 + 32);
        Sa = mfma16(qf0, k0a, Sa);
        Sa = mfma16(qf1, k0b, Sa);
        Sb = mfma16(qf0, k1a, Sb);
        Sb = mfma16(qf1, k1b, Sb);

        float pa[4], pb[4];
#pragma unroll
        for (int r = 0; r < 4; ++r) {
            int qrow = row0 + fq * 4 + r;
            bool alA = (kbase + fr) < qrow;
            bool alB = (kbase + 16 + fr) < qrow;
            float sa = alA ? Sa[r] * 0.125f : -1e30f;
            float sb = alB ? Sb[r] * 0.125f : -1e30f;
            float tm = fmaxf(sa, sb);
#pragma unroll
            for (int off = 1; off < 16; off <<= 1) tm = fmaxf(tm, __shfl_xor(tm, off, 16));
            float Mn = fmaxf(M[r], tm);
            float ea = alA ? __expf(sa - Mn) : 0.f;
            float eb = alB ? __expf(sb - Mn) : 0.f;
            float rs = ea + eb;
#pragma unroll
            for (int off = 1; off < 16; off <<= 1) rs += __shfl_xor(rs, off, 16);
            float alpha = __expf(M[r] - Mn);
            L[r] = L[r] * alpha + rs;
            M[r] = Mn;
            O[0][r] *= alpha; O[1][r] *= alpha; O[2][r] *= alpha; O[3][r] *= alpha;
            pa[r] = ea; pb[r] = eb;
        }
        // P -> LDS (bf16), then read back as MFMA A-fragment
#pragma unroll
        for (int r = 0; r < 4; ++r) {
            Pl[w][fq * 4 + r][fr] = f2bf(pa[r]);
            Pl[w][fq * 4 + r][16 + fr] = f2bf(pb[r]);
        }
        bf16x8 pf = *(const bf16x8*)&Pl[w][fr][fq * 8];
#pragma unroll
        for (int f = 0; f < 4; ++f) {
            bf16x8 vf = *(const bf16x8*)&VT[f * 16 + fr][fq * 8];
            O[f] = mfma16(pf, vf, O[f]);
        }
    }

#pragma unroll
    for (int f = 0; f < 4; ++f)
#pragma unroll
        for (int r = 0; r < 4; ++r) {
            int d = f * 16 + fr;
            int s = row0 + fq * 4 + r;
            float val = (L[r] > 0.f) ? O[f][r] / L[r] : 0.f;
            out[((size_t)b * 512 + h * 64 + d) * 1024 + s] = val;
        }
}

extern "C" void kernel_launch(void* const* d_in, const int* in_sizes, int n_in,
                              void* d_out, int out_size, void* d_ws, size_t ws_size,
                              hipStream_t stream) {
    const float* q    = (const float*)d_in[0];
    const float* k    = (const float*)d_in[1];
    const float* Wq_v = (const float*)d_in[2];
    const float* Wq_g = (const float*)d_in[3];
    const float* bq   = (const float*)d_in[4];
    const float* Wk_v = (const float*)d_in[5];
    const float* Wk_g = (const float*)d_in[6];
    const float* bk   = (const float*)d_in[7];
    const float* Wv_v = (const float*)d_in[8];
    const float* Wv_g = (const float*)d_in[9];
    const float* bv   = (const float*)d_in[10];
    float* out = (float*)d_out;

    char* ws = (char*)d_ws;
    unsigned short* qT = (unsigned short*)(ws + 0);                  // 8*1024*384 bf16
    unsigned short* kT = (unsigned short*)(ws + 6291456);
    unsigned short* Wn = (unsigned short*)(ws + 12582912);           // 3*512*384 bf16
    unsigned short* Qp = (unsigned short*)(ws + 13762560);           // 8*1024*512 bf16
    unsigned short* Kp = (unsigned short*)(ws + 22151168);
    unsigned short* Vp = (unsigned short*)(ws + 30539776);

    wn_kernel<<<dim3(1536), dim3(64), 0, stream>>>(Wq_v, Wq_g, Wk_v, Wk_g, Wv_v, Wv_g, Wn);
    transpose_kernel<<<dim3(32, 12, 16), dim3(32, 8), 0, stream>>>(q, k, qT, kT);
    proj_gemm<<<dim3(8, 4, 24), dim3(256), 0, stream>>>(qT, kT, Wn, bq, bk, bv, Qp, Kp, Vp);
    attn_kernel<<<dim3(16, 64), dim3(256), 0, stream>>>(Qp, Kp, Vp, out);
}

// Round 2
// 117.428 us; speedup vs baseline: 1.2708x; 1.2708x over previous
//
#include <hip/hip_runtime.h>
#include <hip/hip_bf16.h>

typedef __attribute__((ext_vector_type(8))) __bf16 bf16x8;
typedef __attribute__((ext_vector_type(4))) float f32x4;

__device__ __forceinline__ f32x4 mfma16(bf16x8 a, bf16x8 b, f32x4 c) {
    return __builtin_amdgcn_mfma_f32_16x16x32_bf16(a, b, c, 0, 0, 0);
}

__device__ __forceinline__ unsigned short f2bf(float x) {
    union { float f; unsigned int u; } cv; cv.f = x;
    unsigned int r = cv.u + 0x7FFFu + ((cv.u >> 16) & 1u);
    return (unsigned short)(r >> 16);
}

__device__ __forceinline__ unsigned pack2(float a, float b) {
    return (unsigned)f2bf(a) | ((unsigned)f2bf(b) << 16);
}

__device__ __forceinline__ void gload_lds16(const void* g, void* l) {
    __builtin_amdgcn_global_load_lds(
        (const __attribute__((address_space(1))) unsigned int*)g,
        (__attribute__((address_space(3))) unsigned int*)l, 16, 0, 0);
}

// ---------------- Kernel 1: weight norm -> bf16 normalized weights ----------
__global__ __launch_bounds__(64) void wn_kernel(
    const float* __restrict__ Wq_v, const float* __restrict__ Wq_g,
    const float* __restrict__ Wk_v, const float* __restrict__ Wk_g,
    const float* __restrict__ Wv_v, const float* __restrict__ Wv_g,
    unsigned short* __restrict__ Wn)
{
    int idx = blockIdx.x;            // proj*512 + o
    int proj = idx >> 9, o = idx & 511;
    const float* v = (proj == 0 ? Wq_v : proj == 1 ? Wk_v : Wv_v) + (size_t)o * 384;
    const float* g = (proj == 0 ? Wq_g : proj == 1 ? Wk_g : Wv_g);
    int lane = threadIdx.x;
    float vals[6];
    float ss = 0.f;
#pragma unroll
    for (int i = 0; i < 6; ++i) { vals[i] = v[lane + i * 64]; ss += vals[i] * vals[i]; }
#pragma unroll
    for (int off = 1; off < 64; off <<= 1) ss += __shfl_xor(ss, off, 64);
    float scale = g[o] * rsqrtf(ss);
    unsigned short* dst = Wn + ((size_t)proj * 512 + o) * 384;
#pragma unroll
    for (int i = 0; i < 6; ++i) dst[lane + i * 64] = f2bf(vals[i] * scale);
}

// ---------------- Kernel 2: transpose+convert q,k: [B][Cin][S] f32 -> [B][S][Cin] bf16
__global__ __launch_bounds__(256) void transpose_kernel(
    const float* __restrict__ q, const float* __restrict__ k,
    unsigned short* __restrict__ qT, unsigned short* __restrict__ kT)
{
    __shared__ float tile[32][33];
    int z = blockIdx.z;
    const float* src = (z < 8 ? q : k) + (size_t)(z & 7) * 384 * 1024;
    unsigned short* dst = (z < 8 ? qT : kT) + (size_t)(z & 7) * 1024 * 384;
    int c0 = blockIdx.y * 32, s0 = blockIdx.x * 32;
    int tx = threadIdx.x, ty = threadIdx.y;
#pragma unroll
    for (int j = 0; j < 4; ++j)
        tile[ty + j * 8][tx] = src[(size_t)(c0 + ty + j * 8) * 1024 + s0 + tx];
    __syncthreads();
#pragma unroll
    for (int j = 0; j < 4; ++j)
        dst[(size_t)(s0 + ty + j * 8) * 384 + c0 + tx] = f2bf(tile[tx][ty + j * 8]);
}

// ---------------- Kernel 3: projection GEMM (bf16 MFMA) ---------------------
// Out[b][s][c] = sum_i A[b][s][i] * W[c][i] + bias[c]; M=1024,N=512,K=384
// proj==2 (V) writes its output TRANSPOSED: Vt[b][c][s]  (for attn PV A-frags)
__global__ __launch_bounds__(256) void proj_gemm(
    const unsigned short* __restrict__ qT, const unsigned short* __restrict__ kT,
    const unsigned short* __restrict__ Wn,
    const float* __restrict__ bq, const float* __restrict__ bk, const float* __restrict__ bv,
    unsigned short* __restrict__ Qp, unsigned short* __restrict__ Kp,
    unsigned short* __restrict__ Vt)
{
    __shared__ unsigned short Asm[128 * 32];
    __shared__ unsigned short Bsm[128 * 32];
    int zb = blockIdx.z; int proj = zb >> 3, b = zb & 7;
    const unsigned short* A = (proj == 0 ? qT : kT) + (size_t)b * 1024 * 384;
    const unsigned short* Bw = Wn + (size_t)proj * 512 * 384;
    const float* bias = proj == 0 ? bq : (proj == 1 ? bk : bv);
    int m0 = blockIdx.x * 128, n0 = blockIdx.y * 128;
    int t = threadIdx.x, w = t >> 6, lane = t & 63;
    int fr = lane & 15, fq = lane >> 4;
    int wm = (w >> 1) * 64, wn = (w & 1) * 64;

    f32x4 acc[4][4];
#pragma unroll
    for (int i = 0; i < 4; ++i)
#pragma unroll
        for (int j = 0; j < 4; ++j) acc[i][j] = (f32x4){0.f, 0.f, 0.f, 0.f};

    const unsigned short* asrc = A + (size_t)(m0 + w * 16 + (lane >> 2)) * 384 + (lane & 3) * 8;
    const unsigned short* bsrc = Bw + (size_t)(n0 + w * 16 + (lane >> 2)) * 384 + (lane & 3) * 8;
    unsigned short* albase = Asm + w * 512;   // w*1024 bytes, wave-uniform
    unsigned short* blbase = Bsm + w * 512;

    for (int k0 = 0; k0 < 384; k0 += 32) {
        __syncthreads();
        gload_lds16(asrc + k0, albase);
        gload_lds16(asrc + k0 + (size_t)64 * 384, albase + 2048);
        gload_lds16(bsrc + k0, blbase);
        gload_lds16(bsrc + k0 + (size_t)64 * 384, blbase + 2048);
        asm volatile("s_waitcnt vmcnt(0)" ::: "memory");
        __syncthreads();
        bf16x8 af[4], bfr[4];
#pragma unroll
        for (int i = 0; i < 4; ++i)
            af[i] = *(const bf16x8*)&Asm[(wm + i * 16 + fr) * 32 + fq * 8];
#pragma unroll
        for (int i = 0; i < 4; ++i)
            bfr[i] = *(const bf16x8*)&Bsm[(wn + i * 16 + fr) * 32 + fq * 8];
#pragma unroll
        for (int mi = 0; mi < 4; ++mi)
#pragma unroll
            for (int ni = 0; ni < 4; ++ni)
                acc[mi][ni] = mfma16(af[mi], bfr[ni], acc[mi][ni]);
    }
    if (proj == 2) {
        // transposed packed store: Vt[b][c][s], 4 consecutive s per lane -> 8B
#pragma unroll
        for (int mi = 0; mi < 4; ++mi)
#pragma unroll
            for (int ni = 0; ni < 4; ++ni) {
                int c = n0 + wn + ni * 16 + fr;
                int s0 = m0 + wm + mi * 16 + fq * 4;
                float bc = bias[c];
                unsigned lo = pack2(acc[mi][ni][0] + bc, acc[mi][ni][1] + bc);
                unsigned hi = pack2(acc[mi][ni][2] + bc, acc[mi][ni][3] + bc);
                uint2 u; u.x = lo; u.y = hi;
                *(uint2*)&Vt[(((size_t)b * 512 + c) * 1024 + s0)] = u;
            }
    } else {
        unsigned short* Out = (proj == 0 ? Qp : Kp) + (size_t)b * 1024 * 512;
#pragma unroll
        for (int mi = 0; mi < 4; ++mi)
#pragma unroll
            for (int ni = 0; ni < 4; ++ni)
#pragma unroll
                for (int r = 0; r < 4; ++r) {
                    int c = n0 + wn + ni * 16 + fr;
                    int s = m0 + wm + mi * 16 + fq * 4 + r;
                    Out[(size_t)s * 512 + c] = f2bf(acc[mi][ni][r] + bias[c]);
                }
    }
}

// ---------------- Kernel 4: flash attention, transposed-S, barrier-free -----
// 1 wave/block, 32 q-rows/wave, KVBLK=64. S^T = mfma(K,Q): lane holds
// P[key=16kg+4fq+r][q=fr(+16qg)]. Softmax in-lane + 2 shuffles. PV computes
// O^T = mfma(V^T, P) with V^T straight from global (L2-resident), P via a
// wave-private LDS round-trip (packed b64 writes, no barriers anywhere).
__global__ __launch_bounds__(64) void attn_kernel(
    const unsigned short* __restrict__ Qp, const unsigned short* __restrict__ Kp,
    const unsigned short* __restrict__ Vt, float* __restrict__ out)
{
    __shared__ unsigned short Pl[32][72];   // [q][k], 144B rows (16B-aligned)
    int qtile = gridDim.x - 1 - blockIdx.x;  // longest-running blocks first
    int bh = blockIdx.y;
    int b = bh >> 3, h = bh & 7;
    int lane = threadIdx.x;
    int fr = lane & 15, fq = lane >> 4;
    const unsigned short* Qb = Qp + ((size_t)b * 1024) * 512 + h * 64;
    const unsigned short* Kb = Kp + ((size_t)b * 1024) * 512 + h * 64;
    const unsigned short* VTb = Vt + ((size_t)b * 512 + h * 64) * 1024;
    int row0 = qtile * 32;

    // Q fragments (B-operand: col=q=fr), 2 q-groups x 2 c-slices
    bf16x8 qf[2][2];
#pragma unroll
    for (int qg = 0; qg < 2; ++qg)
#pragma unroll
        for (int sl = 0; sl < 2; ++sl)
            qf[qg][sl] = *(const bf16x8*)(Qb + (size_t)(row0 + qg * 16 + fr) * 512 + sl * 32 + fq * 8);

    f32x4 Ot[4][2];   // [d-group][qg]: O^T[d=f*16+fq*4+rr][q=qg*16+fr]
#pragma unroll
    for (int f = 0; f < 4; ++f) { Ot[f][0] = (f32x4){0,0,0,0}; Ot[f][1] = (f32x4){0,0,0,0}; }
    float M[2] = {-1e30f, -1e30f}, L[2] = {0.f, 0.f};

    int nt = ((row0 + 30) >> 6) + 1;   // 64-key tiles covering keys <= row0+30
    for (int kt = 0; kt < nt; ++kt) {
        int kbase = kt * 64;
        // ---- QK^T (transposed): Sacc[qg][kg], D[row=key][col=q]
        f32x4 Sacc[2][4];
#pragma unroll
        for (int qg = 0; qg < 2; ++qg)
#pragma unroll
            for (int kg = 0; kg < 4; ++kg) Sacc[qg][kg] = (f32x4){0,0,0,0};
#pragma unroll
        for (int kg = 0; kg < 4; ++kg) {
            const unsigned short* kr = Kb + (size_t)(kbase + kg * 16 + fr) * 512 + fq * 8;
            bf16x8 k0 = *(const bf16x8*)kr;
            bf16x8 k1 = *(const bf16x8*)(kr + 32);
            Sacc[0][kg] = mfma16(k0, qf[0][0], Sacc[0][kg]);
            Sacc[0][kg] = mfma16(k1, qf[0][1], Sacc[0][kg]);
            Sacc[1][kg] = mfma16(k0, qf[1][0], Sacc[1][kg]);
            Sacc[1][kg] = mfma16(k1, qf[1][1], Sacc[1][kg]);
        }
        // ---- online softmax, per q-group, in-lane over 16 keys + 2 shuffles
#pragma unroll
        for (int qg = 0; qg < 2; ++qg) {
            int qrow = row0 + qg * 16 + fr;
            float e[4][4];
            float vmax = -1e30f;
#pragma unroll
            for (int kg = 0; kg < 4; ++kg)
#pragma unroll
                for (int r = 0; r < 4; ++r) {
                    int key = kbase + kg * 16 + fq * 4 + r;
                    float sv = (key < qrow) ? Sacc[qg][kg][r] * 0.125f : -1e30f;
                    e[kg][r] = sv;
                    vmax = fmaxf(vmax, sv);
                }
            vmax = fmaxf(vmax, __shfl_xor(vmax, 16, 64));
            vmax = fmaxf(vmax, __shfl_xor(vmax, 32, 64));
            float Mn = fmaxf(M[qg], vmax);
            float rs = 0.f;
#pragma unroll
            for (int kg = 0; kg < 4; ++kg)
#pragma unroll
                for (int r = 0; r < 4; ++r) {
                    float ee = (e[kg][r] > -1e29f) ? __expf(e[kg][r] - Mn) : 0.f;
                    e[kg][r] = ee;
                    rs += ee;
                }
            rs += __shfl_xor(rs, 16, 64);
            rs += __shfl_xor(rs, 32, 64);
            float alpha = __expf(M[qg] - Mn);
            L[qg] = L[qg] * alpha + rs;
            M[qg] = Mn;
#pragma unroll
            for (int f = 0; f < 4; ++f) {
                Ot[f][qg][0] *= alpha; Ot[f][qg][1] *= alpha;
                Ot[f][qg][2] *= alpha; Ot[f][qg][3] *= alpha;
            }
            // pack P row-slices -> LDS [q][k] (wave-private, no barrier)
#pragma unroll
            for (int kg = 0; kg < 4; ++kg) {
                uint2 u;
                u.x = pack2(e[kg][0], e[kg][1]);
                u.y = pack2(e[kg][2], e[kg][3]);
                *(uint2*)&Pl[qg * 16 + fr][kg * 16 + fq * 4] = u;
            }
        }
        // ---- PV: O^T += V^T x P   (A=V^T rows=d from global, B=P cols=q)
        bf16x8 pb[2][2];
#pragma unroll
        for (int qg = 0; qg < 2; ++qg)
#pragma unroll
            for (int ks = 0; ks < 2; ++ks)
                pb[qg][ks] = *(const bf16x8*)&Pl[qg * 16 + fr][ks * 32 + fq * 8];
#pragma unroll
        for (int f = 0; f < 4; ++f) {
            bf16x8 a0 = *(const bf16x8*)(VTb + (size_t)(f * 16 + fr) * 1024 + kbase + fq * 8);
            bf16x8 a1 = *(const bf16x8*)(VTb + (size_t)(f * 16 + fr) * 1024 + kbase + 32 + fq * 8);
            Ot[f][0] = mfma16(a0, pb[0][0], Ot[f][0]);
            Ot[f][0] = mfma16(a1, pb[0][1], Ot[f][0]);
            Ot[f][1] = mfma16(a0, pb[1][0], Ot[f][1]);
            Ot[f][1] = mfma16(a1, pb[1][1], Ot[f][1]);
        }
    }

    // ---- epilogue: out[b][h*64+d][q], coalesced along q=fr
#pragma unroll
    for (int qg = 0; qg < 2; ++qg) {
        float rcp = (L[qg] > 0.f) ? 1.f / L[qg] : 0.f;
        int q = row0 + qg * 16 + fr;
#pragma unroll
        for (int f = 0; f < 4; ++f)
#pragma unroll
            for (int rr = 0; rr < 4; ++rr) {
                int d = f * 16 + fq * 4 + rr;
                out[((size_t)b * 512 + h * 64 + d) * 1024 + q] = Ot[f][qg][rr] * rcp;
            }
    }
}

extern "C" void kernel_launch(void* const* d_in, const int* in_sizes, int n_in,
                              void* d_out, int out_size, void* d_ws, size_t ws_size,
                              hipStream_t stream) {
    const float* q    = (const float*)d_in[0];
    const float* k    = (const float*)d_in[1];
    const float* Wq_v = (const float*)d_in[2];
    const float* Wq_g = (const float*)d_in[3];
    const float* bq   = (const float*)d_in[4];
    const float* Wk_v = (const float*)d_in[5];
    const float* Wk_g = (const float*)d_in[6];
    const float* bk   = (const float*)d_in[7];
    const float* Wv_v = (const float*)d_in[8];
    const float* Wv_g = (const float*)d_in[9];
    const float* bv   = (const float*)d_in[10];
    float* out = (float*)d_out;

    char* ws = (char*)d_ws;
    unsigned short* qT = (unsigned short*)(ws + 0);                  // 8*1024*384 bf16
    unsigned short* kT = (unsigned short*)(ws + 6291456);
    unsigned short* Wn = (unsigned short*)(ws + 12582912);           // 3*512*384 bf16
    unsigned short* Qp = (unsigned short*)(ws + 13762560);           // 8*1024*512 bf16
    unsigned short* Kp = (unsigned short*)(ws + 22151168);
    unsigned short* Vt = (unsigned short*)(ws + 30539776);           // [b][c][s]

    wn_kernel<<<dim3(1536), dim3(64), 0, stream>>>(Wq_v, Wq_g, Wk_v, Wk_g, Wv_v, Wv_g, Wn);
    transpose_kernel<<<dim3(32, 12, 16), dim3(32, 8), 0, stream>>>(q, k, qT, kT);
    proj_gemm<<<dim3(8, 4, 24), dim3(256), 0, stream>>>(qT, kT, Wn, bq, bk, bv, Qp, Kp, Vt);
    attn_kernel<<<dim3(32, 64), dim3(64), 0, stream>>>(Qp, Kp, Vt, out);
}

// Round 3
// 81.115 us; speedup vs baseline: 1.8397x; 1.4477x over previous
//
#include <hip/hip_runtime.h>
#include <hip/hip_bf16.h>

typedef __attribute__((ext_vector_type(8))) __bf16 bf16x8;
typedef __attribute__((ext_vector_type(4))) float f32x4;

__device__ __forceinline__ f32x4 mfma16(bf16x8 a, bf16x8 b, f32x4 c) {
    return __builtin_amdgcn_mfma_f32_16x16x32_bf16(a, b, c, 0, 0, 0);
}

__device__ __forceinline__ unsigned short f2bf(float x) {
    union { float f; unsigned int u; } cv; cv.f = x;
    unsigned int r = cv.u + 0x7FFFu + ((cv.u >> 16) & 1u);
    return (unsigned short)(r >> 16);
}

__device__ __forceinline__ unsigned pack2(float a, float b) {
    return (unsigned)f2bf(a) | ((unsigned)f2bf(b) << 16);
}

__device__ __forceinline__ void gload_lds16(const void* g, void* l) {
    __builtin_amdgcn_global_load_lds(
        (const __attribute__((address_space(1))) unsigned int*)g,
        (__attribute__((address_space(3))) unsigned int*)l, 16, 0, 0);
}

// ---------------- Kernel 1: weight norm -> bf16 normalized weights ----------
__global__ __launch_bounds__(64) void wn_kernel(
    const float* __restrict__ Wq_v, const float* __restrict__ Wq_g,
    const float* __restrict__ Wk_v, const float* __restrict__ Wk_g,
    const float* __restrict__ Wv_v, const float* __restrict__ Wv_g,
    unsigned short* __restrict__ Wn)
{
    int idx = blockIdx.x;            // proj*512 + o
    int proj = idx >> 9, o = idx & 511;
    const float* v = (proj == 0 ? Wq_v : proj == 1 ? Wk_v : Wv_v) + (size_t)o * 384;
    const float* g = (proj == 0 ? Wq_g : proj == 1 ? Wk_g : Wv_g);
    int lane = threadIdx.x;
    float vals[6];
    float ss = 0.f;
#pragma unroll
    for (int i = 0; i < 6; ++i) { vals[i] = v[lane + i * 64]; ss += vals[i] * vals[i]; }
#pragma unroll
    for (int off = 1; off < 64; off <<= 1) ss += __shfl_xor(ss, off, 64);
    float scale = g[o] * rsqrtf(ss);
    unsigned short* dst = Wn + ((size_t)proj * 512 + o) * 384;
#pragma unroll
    for (int i = 0; i < 6; ++i) dst[lane + i * 64] = f2bf(vals[i] * scale);
}

// ---------------- Kernel 2: transpose+convert q,k: [B][Cin][S] f32 -> [B][S][Cin] bf16
__global__ __launch_bounds__(256) void transpose_kernel(
    const float* __restrict__ q, const float* __restrict__ k,
    unsigned short* __restrict__ qT, unsigned short* __restrict__ kT)
{
    __shared__ float tile[32][33];
    int z = blockIdx.z;
    const float* src = (z < 8 ? q : k) + (size_t)(z & 7) * 384 * 1024;
    unsigned short* dst = (z < 8 ? qT : kT) + (size_t)(z & 7) * 1024 * 384;
    int c0 = blockIdx.y * 32, s0 = blockIdx.x * 32;
    int tx = threadIdx.x, ty = threadIdx.y;
#pragma unroll
    for (int j = 0; j < 4; ++j)
        tile[ty + j * 8][tx] = src[(size_t)(c0 + ty + j * 8) * 1024 + s0 + tx];
    __syncthreads();
#pragma unroll
    for (int j = 0; j < 4; ++j)
        dst[(size_t)(s0 + ty + j * 8) * 384 + c0 + tx] = f2bf(tile[tx][ty + j * 8]);
}

// ---------------- Kernel 3: projection GEMM (bf16 MFMA, 2-phase pipeline) ---
// Out[b][s][c] = sum_i A[b][s][i] * W[c][i] + bias[c]; M=1024,N=512,K=384
// proj==2 (V) writes its output TRANSPOSED: Vt[b][c][s]
__global__ __launch_bounds__(256) void proj_gemm(
    const unsigned short* __restrict__ qT, const unsigned short* __restrict__ kT,
    const unsigned short* __restrict__ Wn,
    const float* __restrict__ bq, const float* __restrict__ bk, const float* __restrict__ bv,
    unsigned short* __restrict__ Qp, unsigned short* __restrict__ Kp,
    unsigned short* __restrict__ Vt)
{
    __shared__ __align__(16) unsigned short Asm[2][128 * 32];
    __shared__ __align__(16) unsigned short Bsm[2][128 * 32];
    int zb = blockIdx.z; int proj = zb >> 3, b = zb & 7;
    const unsigned short* A = (proj == 0 ? qT : kT) + (size_t)b * 1024 * 384;
    const unsigned short* Bw = Wn + (size_t)proj * 512 * 384;
    const float* bias = proj == 0 ? bq : (proj == 1 ? bk : bv);
    int m0 = blockIdx.x * 128, n0 = blockIdx.y * 128;
    int t = threadIdx.x, w = t >> 6, lane = t & 63;
    int fr = lane & 15, fq = lane >> 4;
    int wm = (w >> 1) * 64, wn = (w & 1) * 64;

    f32x4 acc[4][4];
#pragma unroll
    for (int i = 0; i < 4; ++i)
#pragma unroll
        for (int j = 0; j < 4; ++j) acc[i][j] = (f32x4){0.f, 0.f, 0.f, 0.f};

    const unsigned short* asrc = A + (size_t)(m0 + w * 16 + (lane >> 2)) * 384 + (lane & 3) * 8;
    const unsigned short* bsrc = Bw + (size_t)(n0 + w * 16 + (lane >> 2)) * 384 + (lane & 3) * 8;

    auto stageAB = [&](int k0, int bufi) {
        gload_lds16(asrc + k0, &Asm[bufi][w * 512]);
        gload_lds16(asrc + k0 + (size_t)64 * 384, &Asm[bufi][w * 512 + 2048]);
        gload_lds16(bsrc + k0, &Bsm[bufi][w * 512]);
        gload_lds16(bsrc + k0 + (size_t)64 * 384, &Bsm[bufi][w * 512 + 2048]);
    };

    stageAB(0, 0);
    for (int ks = 0; ks < 12; ++ks) {
        if (ks < 11) {
            stageAB((ks + 1) * 32, (ks + 1) & 1);
            asm volatile("s_waitcnt vmcnt(4)" ::: "memory");
        } else {
            asm volatile("s_waitcnt vmcnt(0)" ::: "memory");
        }
        __builtin_amdgcn_s_barrier();
        int bi = ks & 1;
        bf16x8 af[4], bfr[4];
#pragma unroll
        for (int i = 0; i < 4; ++i)
            af[i] = *(const bf16x8*)&Asm[bi][(wm + i * 16 + fr) * 32 + fq * 8];
#pragma unroll
        for (int i = 0; i < 4; ++i)
            bfr[i] = *(const bf16x8*)&Bsm[bi][(wn + i * 16 + fr) * 32 + fq * 8];
#pragma unroll
        for (int mi = 0; mi < 4; ++mi)
#pragma unroll
            for (int ni = 0; ni < 4; ++ni)
                acc[mi][ni] = mfma16(af[mi], bfr[ni], acc[mi][ni]);
        asm volatile("s_waitcnt lgkmcnt(0)" ::: "memory");
        __builtin_amdgcn_s_barrier();
    }

    if (proj == 2) {
#pragma unroll
        for (int mi = 0; mi < 4; ++mi)
#pragma unroll
            for (int ni = 0; ni < 4; ++ni) {
                int c = n0 + wn + ni * 16 + fr;
                int s0 = m0 + wm + mi * 16 + fq * 4;
                float bc = bias[c];
                unsigned lo = pack2(acc[mi][ni][0] + bc, acc[mi][ni][1] + bc);
                unsigned hi = pack2(acc[mi][ni][2] + bc, acc[mi][ni][3] + bc);
                uint2 u; u.x = lo; u.y = hi;
                *(uint2*)&Vt[(((size_t)b * 512 + c) * 1024 + s0)] = u;
            }
    } else {
        unsigned short* Out = (proj == 0 ? Qp : Kp) + (size_t)b * 1024 * 512;
#pragma unroll
        for (int mi = 0; mi < 4; ++mi)
#pragma unroll
            for (int ni = 0; ni < 4; ++ni)
#pragma unroll
                for (int r = 0; r < 4; ++r) {
                    int c = n0 + wn + ni * 16 + fr;
                    int s = m0 + wm + mi * 16 + fq * 4 + r;
                    Out[(size_t)s * 512 + c] = f2bf(acc[mi][ni][r] + bias[c]);
                }
    }
}

// ---------------- Kernel 4: flash attention, 4-wave blocks, staged KV -------
// Block: 4 waves x QBLK16 = 64 q-rows; KV tiles of 64 staged to LDS
// (double-buffered, XOR-swizzled via pre-swizzled global source).
// Swapped QK^T: lane holds P[key][q=fr]; softmax = in-lane + 2 shuffles.
__global__ __launch_bounds__(256, 4) void attn_kernel(
    const unsigned short* __restrict__ Qp, const unsigned short* __restrict__ Kp,
    const unsigned short* __restrict__ Vt, float* __restrict__ out)
{
    __shared__ __align__(16) unsigned short Kl[2][64 * 64];
    __shared__ __align__(16) unsigned short Vl[2][64 * 64];
    __shared__ __align__(16) unsigned short Pl[4][16 * 64];
    // balanced qb mapping: pairs sum to 15 at stride-1 AND stride-8
    int x = blockIdx.x;
    int qb = (x & 8) ? ((x & 1) ? 15 - (x - 8) : (x - 8))
                     : ((x & 1) ? x : 15 - x);
    int bh = blockIdx.y, b = bh >> 3, h = bh & 7;
    int t = threadIdx.x, w = t >> 6, lane = t & 63;
    int fr = lane & 15, fq = lane >> 4;
    int sub = lane >> 3;                        // 0..7 (stage row within chunk)
    int sw = 8 * ((lane & 7) ^ sub);            // pre-swizzled source col (shorts)
    int swz = 8 * (fr & 7);                     // read-side XOR (shorts)
    const unsigned short* Qb = Qp + ((size_t)b * 1024) * 512 + h * 64;
    const unsigned short* Kb = Kp + ((size_t)b * 1024) * 512 + h * 64;
    const unsigned short* VTb = Vt + ((size_t)b * 512 + h * 64) * 1024;
    int row0 = qb * 64 + w * 16;
    int nt = qb + 1;

    bf16x8 qf0 = *(const bf16x8*)(Qb + (size_t)(row0 + fr) * 512 + fq * 8);
    bf16x8 qf1 = *(const bf16x8*)(Qb + (size_t)(row0 + fr) * 512 + 32 + fq * 8);

    f32x4 Ot[4];
#pragma unroll
    for (int f = 0; f < 4; ++f) Ot[f] = (f32x4){0.f, 0.f, 0.f, 0.f};
    float M = -3e38f, L = 0.f;

    // waves 0,1 stage K chunks; waves 2,3 stage V chunks (4 x 1KB each)
    auto stage = [&](int kt, int bufi) {
        int kbase = kt * 64;
        int c0 = (w & 1) * 4;
        if (w < 2) {
#pragma unroll
            for (int i = 0; i < 4; ++i) {
                int c = c0 + i;
                gload_lds16(Kb + (size_t)(kbase + c * 8 + sub) * 512 + sw,
                            &Kl[bufi][c * 512]);
            }
        } else {
#pragma unroll
            for (int i = 0; i < 4; ++i) {
                int c = c0 + i;
                gload_lds16(VTb + (size_t)(c * 8 + sub) * 1024 + kbase + sw,
                            &Vl[bufi][c * 512]);
            }
        }
    };

    int cur = 0;
    stage(0, 0);
    for (int kt = 0; kt < nt; ++kt) {
        int kbase = kt * 64;
        if (kt + 1 < nt) {
            stage(kt + 1, cur ^ 1);
            asm volatile("s_waitcnt vmcnt(4)" ::: "memory");
        } else {
            asm volatile("s_waitcnt vmcnt(0)" ::: "memory");
        }
        __builtin_amdgcn_s_barrier();

        // ---- QK^T (swapped): Sacc[kg], D[key=kg*16+fq*4+r][q=fr]
        f32x4 Sacc[4];
#pragma unroll
        for (int kg = 0; kg < 4; ++kg) Sacc[kg] = (f32x4){0.f, 0.f, 0.f, 0.f};
#pragma unroll
        for (int kg = 0; kg < 4; ++kg) {
            bf16x8 k0 = *(const bf16x8*)&Kl[cur][(kg * 16 + fr) * 64 + ((fq * 8) ^ swz)];
            bf16x8 k1 = *(const bf16x8*)&Kl[cur][(kg * 16 + fr) * 64 + ((32 + fq * 8) ^ swz)];
            Sacc[kg] = mfma16(k0, qf0, Sacc[kg]);
            Sacc[kg] = mfma16(k1, qf1, Sacc[kg]);
        }

        // ---- online softmax (defer-max THR=8), per q-row = per lane fr
        int qrow = row0 + fr;
        float e[4][4];
        float vmax = -3e38f;
#pragma unroll
        for (int kg = 0; kg < 4; ++kg)
#pragma unroll
            for (int r = 0; r < 4; ++r) {
                int key = kbase + kg * 16 + fq * 4 + r;
                float sv = (key < qrow) ? Sacc[kg][r] * 0.125f : -3e38f;
                e[kg][r] = sv;
                vmax = fmaxf(vmax, sv);
            }
        vmax = fmaxf(vmax, __shfl_xor(vmax, 16, 64));
        vmax = fmaxf(vmax, __shfl_xor(vmax, 32, 64));
        if (__any(vmax > M + 8.f)) {
            float Mn = fmaxf(M, vmax);
            float al = __expf(M - Mn);
            L *= al;
            M = Mn;
#pragma unroll
            for (int f = 0; f < 4; ++f) {
                Ot[f][0] *= al; Ot[f][1] *= al; Ot[f][2] *= al; Ot[f][3] *= al;
            }
        }
        float rs = 0.f;
#pragma unroll
        for (int kg = 0; kg < 4; ++kg)
#pragma unroll
            for (int r = 0; r < 4; ++r) {
                float ee = (e[kg][r] > -1e37f) ? __expf(e[kg][r] - M) : 0.f;
                e[kg][r] = ee;
                rs += ee;
            }
        rs += __shfl_xor(rs, 16, 64);
        rs += __shfl_xor(rs, 32, 64);
        L += rs;

        // ---- P -> LDS (wave-private, swizzled), read back as B-frag
#pragma unroll
        for (int kg = 0; kg < 4; ++kg) {
            uint2 u;
            u.x = pack2(e[kg][0], e[kg][1]);
            u.y = pack2(e[kg][2], e[kg][3]);
            *(uint2*)&Pl[w][fr * 64 + ((kg * 16 + fq * 4) ^ swz)] = u;
        }
        bf16x8 pb0 = *(const bf16x8*)&Pl[w][fr * 64 + ((fq * 8) ^ swz)];
        bf16x8 pb1 = *(const bf16x8*)&Pl[w][fr * 64 + ((32 + fq * 8) ^ swz)];

        // ---- PV: O^T += V^T x P
#pragma unroll
        for (int f = 0; f < 4; ++f) {
            bf16x8 a0 = *(const bf16x8*)&Vl[cur][(f * 16 + fr) * 64 + ((fq * 8) ^ swz)];
            bf16x8 a1 = *(const bf16x8*)&Vl[cur][(f * 16 + fr) * 64 + ((32 + fq * 8) ^ swz)];
            Ot[f] = mfma16(a0, pb0, Ot[f]);
            Ot[f] = mfma16(a1, pb1, Ot[f]);
        }

        asm volatile("s_waitcnt lgkmcnt(0)" ::: "memory");
        __builtin_amdgcn_s_barrier();
        cur ^= 1;
    }

    // ---- epilogue: out[b][h*64+d][q], coalesced along q=fr
    float rcp = (L > 0.f) ? 1.f / L : 0.f;
    int q = row0 + fr;
#pragma unroll
    for (int f = 0; f < 4; ++f)
#pragma unroll
        for (int rr = 0; rr < 4; ++rr) {
            int d = f * 16 + fq * 4 + rr;
            out[((size_t)b * 512 + h * 64 + d) * 1024 + q] = Ot[f][rr] * rcp;
        }
}

extern "C" void kernel_launch(void* const* d_in, const int* in_sizes, int n_in,
                              void* d_out, int out_size, void* d_ws, size_t ws_size,
                              hipStream_t stream) {
    const float* q    = (const float*)d_in[0];
    const float* k    = (const float*)d_in[1];
    const float* Wq_v = (const float*)d_in[2];
    const float* Wq_g = (const float*)d_in[3];
    const float* bq   = (const float*)d_in[4];
    const float* Wk_v = (const float*)d_in[5];
    const float* Wk_g = (const float*)d_in[6];
    const float* bk   = (const float*)d_in[7];
    const float* Wv_v = (const float*)d_in[8];
    const float* Wv_g = (const float*)d_in[9];
    const float* bv   = (const float*)d_in[10];
    float* out = (float*)d_out;

    char* ws = (char*)d_ws;
    unsigned short* qT = (unsigned short*)(ws + 0);                  // 8*1024*384 bf16
    unsigned short* kT = (unsigned short*)(ws + 6291456);
    unsigned short* Wn = (unsigned short*)(ws + 12582912);           // 3*512*384 bf16
    unsigned short* Qp = (unsigned short*)(ws + 13762560);           // 8*1024*512 bf16
    unsigned short* Kp = (unsigned short*)(ws + 22151168);
    unsigned short* Vt = (unsigned short*)(ws + 30539776);           // [b][c][s]

    wn_kernel<<<dim3(1536), dim3(64), 0, stream>>>(Wq_v, Wq_g, Wk_v, Wk_g, Wv_v, Wv_g, Wn);
    transpose_kernel<<<dim3(32, 12, 16), dim3(32, 8), 0, stream>>>(q, k, qT, kT);
    proj_gemm<<<dim3(8, 4, 24), dim3(256), 0, stream>>>(qT, kT, Wn, bq, bk, bv, Qp, Kp, Vt);
    attn_kernel<<<dim3(16, 64), dim3(256), 0, stream>>>(Qp, Kp, Vt, out);
}

// Round 4
// 66.306 us; speedup vs baseline: 2.2506x; 1.2233x over previous
//
#include <hip/hip_runtime.h>
#include <hip/hip_bf16.h>

typedef __attribute__((ext_vector_type(8))) __bf16 bf16x8;
typedef __attribute__((ext_vector_type(4))) float f32x4;

__device__ __forceinline__ f32x4 mfma16(bf16x8 a, bf16x8 b, f32x4 c) {
    return __builtin_amdgcn_mfma_f32_16x16x32_bf16(a, b, c, 0, 0, 0);
}

__device__ __forceinline__ unsigned short f2bf(float x) {
    union { float f; unsigned int u; } cv; cv.f = x;
    unsigned int r = cv.u + 0x7FFFu + ((cv.u >> 16) & 1u);
    return (unsigned short)(r >> 16);
}

__device__ __forceinline__ unsigned pack2(float a, float b) {
    return (unsigned)f2bf(a) | ((unsigned)f2bf(b) << 16);
}

__device__ __forceinline__ unsigned pk2(float a, float b) {
    float2 f2; f2.x = a; f2.y = b;
    __hip_bfloat162 h = __float22bfloat162_rn(f2);
    return *(unsigned*)&h;
}

__device__ __forceinline__ float fast_exp2(float x) {
    float r;
    asm("v_exp_f32 %0, %1" : "=v"(r) : "v"(x));
    return r;
}

__device__ __forceinline__ void gload_lds16(const void* g, void* l) {
    __builtin_amdgcn_global_load_lds(
        (const __attribute__((address_space(1))) unsigned int*)g,
        (__attribute__((address_space(3))) unsigned int*)l, 16, 0, 0);
}

// ---------------- Kernel 1: fused weight-norm + q/k transpose ---------------
// z in [0,16): transpose+convert q,k: [B][Cin][S] f32 -> [B][S][Cin] bf16
// z == 16   : weight norm -> bf16 normalized weights (384 blocks x 4 rows)
__global__ __launch_bounds__(256) void prep_kernel(
    const float* __restrict__ q, const float* __restrict__ k,
    const float* __restrict__ Wq_v, const float* __restrict__ Wq_g,
    const float* __restrict__ Wk_v, const float* __restrict__ Wk_g,
    const float* __restrict__ Wv_v, const float* __restrict__ Wv_g,
    unsigned short* __restrict__ qT, unsigned short* __restrict__ kT,
    unsigned short* __restrict__ Wn)
{
    __shared__ float tile[32][33];
    int z = blockIdx.z;
    int t = threadIdx.x;
    if (z == 16) {
        int w = t >> 6, lane = t & 63;
        int idx = (blockIdx.y * 32 + blockIdx.x) * 4 + w;   // 0..1535
        int proj = idx >> 9, o = idx & 511;
        const float* v = (proj == 0 ? Wq_v : proj == 1 ? Wk_v : Wv_v) + (size_t)o * 384;
        const float* g = (proj == 0 ? Wq_g : proj == 1 ? Wk_g : Wv_g);
        float vals[6];
        float ss = 0.f;
#pragma unroll
        for (int i = 0; i < 6; ++i) { vals[i] = v[lane + i * 64]; ss += vals[i] * vals[i]; }
#pragma unroll
        for (int off = 1; off < 64; off <<= 1) ss += __shfl_xor(ss, off, 64);
        float scale = g[o] * rsqrtf(ss);
        unsigned short* dst = Wn + ((size_t)proj * 512 + o) * 384;
#pragma unroll
        for (int i = 0; i < 6; ++i) dst[lane + i * 64] = f2bf(vals[i] * scale);
        return;
    }
    int tx = t & 31, ty = t >> 5;
    const float* src = (z < 8 ? q : k) + (size_t)(z & 7) * 384 * 1024;
    unsigned short* dst = (z < 8 ? qT : kT) + (size_t)(z & 7) * 1024 * 384;
    int c0 = blockIdx.y * 32, s0 = blockIdx.x * 32;
#pragma unroll
    for (int j = 0; j < 4; ++j)
        tile[ty + j * 8][tx] = src[(size_t)(c0 + ty + j * 8) * 1024 + s0 + tx];
    __syncthreads();
#pragma unroll
    for (int j = 0; j < 4; ++j)
        dst[(size_t)(s0 + ty + j * 8) * 384 + c0 + tx] = f2bf(tile[tx][ty + j * 8]);
}

// ---------------- Kernel 3: projection GEMM (bf16 MFMA, 2-phase pipeline) ---
// Out[b][s][c] = sum_i A[b][s][i] * W[c][i] + bias[c]; M=1024,N=512,K=384
// proj==2 (V) writes its output TRANSPOSED: Vt[b][c][s]
__global__ __launch_bounds__(256) void proj_gemm(
    const unsigned short* __restrict__ qT, const unsigned short* __restrict__ kT,
    const unsigned short* __restrict__ Wn,
    const float* __restrict__ bq, const float* __restrict__ bk, const float* __restrict__ bv,
    unsigned short* __restrict__ Qp, unsigned short* __restrict__ Kp,
    unsigned short* __restrict__ Vt)
{
    __shared__ __align__(16) unsigned short Asm[2][128 * 32];
    __shared__ __align__(16) unsigned short Bsm[2][128 * 32];
    int zb = blockIdx.z; int proj = zb >> 3, b = zb & 7;
    const unsigned short* A = (proj == 0 ? qT : kT) + (size_t)b * 1024 * 384;
    const unsigned short* Bw = Wn + (size_t)proj * 512 * 384;
    const float* bias = proj == 0 ? bq : (proj == 1 ? bk : bv);
    int m0 = blockIdx.x * 128, n0 = blockIdx.y * 128;
    int t = threadIdx.x, w = t >> 6, lane = t & 63;
    int fr = lane & 15, fq = lane >> 4;
    int wm = (w >> 1) * 64, wn = (w & 1) * 64;

    f32x4 acc[4][4];
#pragma unroll
    for (int i = 0; i < 4; ++i)
#pragma unroll
        for (int j = 0; j < 4; ++j) acc[i][j] = (f32x4){0.f, 0.f, 0.f, 0.f};

    const unsigned short* asrc = A + (size_t)(m0 + w * 16 + (lane >> 2)) * 384 + (lane & 3) * 8;
    const unsigned short* bsrc = Bw + (size_t)(n0 + w * 16 + (lane >> 2)) * 384 + (lane & 3) * 8;

    auto stageAB = [&](int k0, int bufi) {
        gload_lds16(asrc + k0, &Asm[bufi][w * 512]);
        gload_lds16(asrc + k0 + (size_t)64 * 384, &Asm[bufi][w * 512 + 2048]);
        gload_lds16(bsrc + k0, &Bsm[bufi][w * 512]);
        gload_lds16(bsrc + k0 + (size_t)64 * 384, &Bsm[bufi][w * 512 + 2048]);
    };

    stageAB(0, 0);
    for (int ks = 0; ks < 12; ++ks) {
        if (ks < 11) {
            stageAB((ks + 1) * 32, (ks + 1) & 1);
            asm volatile("s_waitcnt vmcnt(4)" ::: "memory");
        } else {
            asm volatile("s_waitcnt vmcnt(0)" ::: "memory");
        }
        __builtin_amdgcn_s_barrier();
        int bi = ks & 1;
        bf16x8 af[4], bfr[4];
#pragma unroll
        for (int i = 0; i < 4; ++i)
            af[i] = *(const bf16x8*)&Asm[bi][(wm + i * 16 + fr) * 32 + fq * 8];
#pragma unroll
        for (int i = 0; i < 4; ++i)
            bfr[i] = *(const bf16x8*)&Bsm[bi][(wn + i * 16 + fr) * 32 + fq * 8];
#pragma unroll
        for (int mi = 0; mi < 4; ++mi)
#pragma unroll
            for (int ni = 0; ni < 4; ++ni)
                acc[mi][ni] = mfma16(af[mi], bfr[ni], acc[mi][ni]);
        asm volatile("s_waitcnt lgkmcnt(0)" ::: "memory");
        __builtin_amdgcn_s_barrier();
    }

    if (proj == 2) {
#pragma unroll
        for (int mi = 0; mi < 4; ++mi)
#pragma unroll
            for (int ni = 0; ni < 4; ++ni) {
                int c = n0 + wn + ni * 16 + fr;
                int s0 = m0 + wm + mi * 16 + fq * 4;
                float bc = bias[c];
                unsigned lo = pack2(acc[mi][ni][0] + bc, acc[mi][ni][1] + bc);
                unsigned hi = pack2(acc[mi][ni][2] + bc, acc[mi][ni][3] + bc);
                uint2 u; u.x = lo; u.y = hi;
                *(uint2*)&Vt[(((size_t)b * 512 + c) * 1024 + s0)] = u;
            }
    } else {
        unsigned short* Out = (proj == 0 ? Qp : Kp) + (size_t)b * 1024 * 512;
#pragma unroll
        for (int mi = 0; mi < 4; ++mi)
#pragma unroll
            for (int ni = 0; ni < 4; ++ni)
#pragma unroll
                for (int r = 0; r < 4; ++r) {
                    int c = n0 + wn + ni * 16 + fr;
                    int s = m0 + wm + mi * 16 + fq * 4 + r;
                    Out[(size_t)s * 512 + c] = f2bf(acc[mi][ni][r] + bias[c]);
                }
    }
}

// ---------------- Kernel 4: flash attention, paired q-tiles (balanced) ------
// Block: 4 waves x QBLK16 = 64 q-rows per phase; processes q-tile pj then
// 15-pj -> every block does exactly 17 kv-tile-units. Swapped QK^T, softmax
// in log2 domain (raw v_exp_f32, M init -128 so masked rows exp to 0).
__global__ __launch_bounds__(256, 4) void attn_kernel(
    const unsigned short* __restrict__ Qp, const unsigned short* __restrict__ Kp,
    const unsigned short* __restrict__ Vt, float* __restrict__ out)
{
    __shared__ __align__(16) unsigned short Kl[2][64 * 64];
    __shared__ __align__(16) unsigned short Vl[2][64 * 64];
    __shared__ __align__(16) unsigned short Pl[4][16 * 64];
    const float SCL = 0.125f * 1.44269504089f;   // 1/sqrt(64) * log2(e)
    int pj = blockIdx.x;                          // 0..7
    int bh = blockIdx.y, b = bh >> 3, h = bh & 7;
    int t = threadIdx.x, w = t >> 6, lane = t & 63;
    int fr = lane & 15, fq = lane >> 4;
    int sub = lane >> 3;                        // 0..7 (stage row within chunk)
    int sw = 8 * ((lane & 7) ^ sub);            // pre-swizzled source col (shorts)
    int swz = 8 * (fr & 7);                     // read-side XOR (shorts)
    const unsigned short* Qb = Qp + ((size_t)b * 1024) * 512 + h * 64;
    const unsigned short* Kb = Kp + ((size_t)b * 1024) * 512 + h * 64;
    const unsigned short* VTb = Vt + ((size_t)b * 512 + h * 64) * 1024;

    // waves 0,1 stage K chunks; waves 2,3 stage V chunks (4 x 1KB each)
    auto stage = [&](int kt, int bufi) {
        int kbase = kt * 64;
        int c0 = (w & 1) * 4;
        if (w < 2) {
#pragma unroll
            for (int i = 0; i < 4; ++i) {
                int c = c0 + i;
                gload_lds16(Kb + (size_t)(kbase + c * 8 + sub) * 512 + sw,
                            &Kl[bufi][c * 512]);
            }
        } else {
#pragma unroll
            for (int i = 0; i < 4; ++i) {
                int c = c0 + i;
                gload_lds16(VTb + (size_t)(c * 8 + sub) * 1024 + kbase + sw,
                            &Vl[bufi][c * 512]);
            }
        }
    };

    int cur = 0;
#pragma unroll 1
    for (int ph = 0; ph < 2; ++ph) {
        int qtile = ph == 0 ? pj : 15 - pj;
        int row0 = qtile * 64 + w * 16;
        int nt = qtile + 1;

        bf16x8 qf0 = *(const bf16x8*)(Qb + (size_t)(row0 + fr) * 512 + fq * 8);
        bf16x8 qf1 = *(const bf16x8*)(Qb + (size_t)(row0 + fr) * 512 + 32 + fq * 8);

        f32x4 Ot[4];
#pragma unroll
        for (int f = 0; f < 4; ++f) Ot[f] = (f32x4){0.f, 0.f, 0.f, 0.f};
        float M = -128.f, L = 0.f;

        stage(0, cur);
        for (int kt = 0; kt < nt; ++kt) {
            int kbase = kt * 64;
            if (kt + 1 < nt) {
                stage(kt + 1, cur ^ 1);
                asm volatile("s_waitcnt vmcnt(4)" ::: "memory");
            } else {
                asm volatile("s_waitcnt vmcnt(0)" ::: "memory");
            }
            __builtin_amdgcn_s_barrier();

            // ---- QK^T (swapped): Sacc[kg], D[key=kg*16+fq*4+r][q=fr]
            f32x4 Sacc[4];
#pragma unroll
            for (int kg = 0; kg < 4; ++kg) Sacc[kg] = (f32x4){0.f, 0.f, 0.f, 0.f};
#pragma unroll
            for (int kg = 0; kg < 4; ++kg) {
                bf16x8 k0 = *(const bf16x8*)&Kl[cur][(kg * 16 + fr) * 64 + ((fq * 8) ^ swz)];
                bf16x8 k1 = *(const bf16x8*)&Kl[cur][(kg * 16 + fr) * 64 + ((32 + fq * 8) ^ swz)];
                Sacc[kg] = mfma16(k0, qf0, Sacc[kg]);
                Sacc[kg] = mfma16(k1, qf1, Sacc[kg]);
            }

            // ---- online softmax in log2 domain, defer-max THR=8
            int qrow = row0 + fr;
            float e[4][4];
            float vmax = -3e38f;
#pragma unroll
            for (int kg = 0; kg < 4; ++kg)
#pragma unroll
                for (int r = 0; r < 4; ++r) {
                    int key = kbase + kg * 16 + fq * 4 + r;
                    float sv = (key < qrow) ? Sacc[kg][r] * SCL : -3e38f;
                    e[kg][r] = sv;
                    vmax = fmaxf(vmax, sv);
                }
            vmax = fmaxf(vmax, __shfl_xor(vmax, 16, 64));
            vmax = fmaxf(vmax, __shfl_xor(vmax, 32, 64));
            if (__any(vmax > M + 8.f)) {
                float Mn = fmaxf(M, vmax);
                float al = fast_exp2(M - Mn);
                L *= al;
                M = Mn;
#pragma unroll
                for (int f = 0; f < 4; ++f) {
                    Ot[f][0] *= al; Ot[f][1] *= al; Ot[f][2] *= al; Ot[f][3] *= al;
                }
            }
            float rs = 0.f;
#pragma unroll
            for (int kg = 0; kg < 4; ++kg)
#pragma unroll
                for (int r = 0; r < 4; ++r) {
                    float ee = fast_exp2(e[kg][r] - M);   // masked: -3e38-M -> 0
                    e[kg][r] = ee;
                    rs += ee;
                }
            rs += __shfl_xor(rs, 16, 64);
            rs += __shfl_xor(rs, 32, 64);
            L += rs;

            // ---- P -> LDS (wave-private, swizzled), read back as B-frag
#pragma unroll
            for (int kg = 0; kg < 4; ++kg) {
                uint2 u;
                u.x = pk2(e[kg][0], e[kg][1]);
                u.y = pk2(e[kg][2], e[kg][3]);
                *(uint2*)&Pl[w][fr * 64 + ((kg * 16 + fq * 4) ^ swz)] = u;
            }
            bf16x8 pb0 = *(const bf16x8*)&Pl[w][fr * 64 + ((fq * 8) ^ swz)];
            bf16x8 pb1 = *(const bf16x8*)&Pl[w][fr * 64 + ((32 + fq * 8) ^ swz)];

            // ---- PV: O^T += V^T x P
#pragma unroll
            for (int f = 0; f < 4; ++f) {
                bf16x8 a0 = *(const bf16x8*)&Vl[cur][(f * 16 + fr) * 64 + ((fq * 8) ^ swz)];
                bf16x8 a1 = *(const bf16x8*)&Vl[cur][(f * 16 + fr) * 64 + ((32 + fq * 8) ^ swz)];
                Ot[f] = mfma16(a0, pb0, Ot[f]);
                Ot[f] = mfma16(a1, pb1, Ot[f]);
            }

            asm volatile("s_waitcnt lgkmcnt(0)" ::: "memory");
            __builtin_amdgcn_s_barrier();
            cur ^= 1;
        }

        // ---- epilogue: out[b][h*64+d][q], coalesced along q=fr
        float rcp = (L > 0.f) ? 1.f / L : 0.f;
        int q = row0 + fr;
#pragma unroll
        for (int f = 0; f < 4; ++f)
#pragma unroll
            for (int rr = 0; rr < 4; ++rr) {
                int d = f * 16 + fq * 4 + rr;
                out[((size_t)b * 512 + h * 64 + d) * 1024 + q] = Ot[f][rr] * rcp;
            }
    }
}

extern "C" void kernel_launch(void* const* d_in, const int* in_sizes, int n_in,
                              void* d_out, int out_size, void* d_ws, size_t ws_size,
                              hipStream_t stream) {
    const float* q    = (const float*)d_in[0];
    const float* k    = (const float*)d_in[1];
    const float* Wq_v = (const float*)d_in[2];
    const float* Wq_g = (const float*)d_in[3];
    const float* bq   = (const float*)d_in[4];
    const float* Wk_v = (const float*)d_in[5];
    const float* Wk_g = (const float*)d_in[6];
    const float* bk   = (const float*)d_in[7];
    const float* Wv_v = (const float*)d_in[8];
    const float* Wv_g = (const float*)d_in[9];
    const float* bv   = (const float*)d_in[10];
    float* out = (float*)d_out;

    char* ws = (char*)d_ws;
    unsigned short* qT = (unsigned short*)(ws + 0);                  // 8*1024*384 bf16
    unsigned short* kT = (unsigned short*)(ws + 6291456);
    unsigned short* Wn = (unsigned short*)(ws + 12582912);           // 3*512*384 bf16
    unsigned short* Qp = (unsigned short*)(ws + 13762560);           // 8*1024*512 bf16
    unsigned short* Kp = (unsigned short*)(ws + 22151168);
    unsigned short* Vt = (unsigned short*)(ws + 30539776);           // [b][c][s]

    prep_kernel<<<dim3(32, 12, 17), dim3(256), 0, stream>>>(
        q, k, Wq_v, Wq_g, Wk_v, Wk_g, Wv_v, Wv_g, qT, kT, Wn);
    proj_gemm<<<dim3(8, 4, 24), dim3(256), 0, stream>>>(qT, kT, Wn, bq, bk, bv, Qp, Kp, Vt);
    attn_kernel<<<dim3(8, 64), dim3(256), 0, stream>>>(Qp, Kp, Vt, out);
}